// Round 1
// baseline (21987.497 us; speedup 1.0000x reference)
//
#include <hip/hip_runtime.h>

// ---------------------------------------------------------------------------
// Generic tiled 3x3 SAME conv, NCHW fp32.
//   - 16x16 spatial tile per block (256 threads), COB output channels/thread
//   - input staged in LDS in chunks of ICB channels (with optional ReLU on read)
//   - optional ReLU on write, optional pixel-shuffle(r=2) write layout,
//     optional accumulate-into-output (residual add)
// ---------------------------------------------------------------------------
template<int CIN, int ICB, int COUT, int COB, bool RELU_IN, bool RELU_OUT,
         int SHUF, bool ACCUM>
__global__ __launch_bounds__(256) void conv3x3_k(
    const float* __restrict__ in, const float* __restrict__ wgt,
    const float* __restrict__ bias, float* __restrict__ out,
    int H, int W)
{
    constexpr int NOCG = COUT / COB;
    const int tid = threadIdx.x;
    const int tx = tid & 15;
    const int ty = tid >> 4;
    const int w0 = blockIdx.x * 16;
    const int h0 = blockIdx.y * 16;
    const int ocg = blockIdx.z % NOCG;
    const int b   = blockIdx.z / NOCG;
    const int oc0 = ocg * COB;
    const int px = w0 + tx;
    const int py = h0 + ty;

    __shared__ float lds[ICB][18][18];
    __shared__ float wl[COB][ICB][9];

    float acc[COB];
#pragma unroll
    for (int i = 0; i < COB; i++) acc[i] = bias[oc0 + i];

    for (int ic0 = 0; ic0 < CIN; ic0 += ICB) {
        // stage weights for this (oc-group, ic-chunk)
        for (int i = tid; i < COB * ICB * 9; i += 256) {
            int oc = i / (ICB * 9);
            int r  = i - oc * (ICB * 9);
            int ic = r / 9;
            int t  = r - ic * 9;
            wl[oc][ic][t] = wgt[((size_t)(oc0 + oc) * CIN + (ic0 + ic)) * 9 + t];
        }
        // stage 18x18 input halo tile for ICB channels
        for (int i = tid; i < ICB * 324; i += 256) {
            int ic = i / 324;
            int r  = i - ic * 324;
            int y  = r / 18;
            int x  = r - y * 18;
            int gy = h0 + y - 1, gx = w0 + x - 1;
            float v = 0.f;
            if (gy >= 0 && gy < H && gx >= 0 && gx < W) {
                v = in[((size_t)(b * CIN + ic0 + ic) * H + gy) * W + gx];
                if (RELU_IN) v = fmaxf(v, 0.f);
            }
            lds[ic][y][x] = v;
        }
        __syncthreads();
#pragma unroll
        for (int ic = 0; ic < ICB; ic++) {
#pragma unroll
            for (int t = 0; t < 9; t++) {
                float v = lds[ic][ty + t / 3][tx + t % 3];
#pragma unroll
                for (int oc = 0; oc < COB; oc++)
                    acc[oc] = fmaf(v, wl[oc][ic][t], acc[oc]);
            }
        }
        __syncthreads();
    }

#pragma unroll
    for (int oc = 0; oc < COB; oc++) {
        float v = acc[oc];
        if (RELU_OUT) v = fmaxf(v, 0.f);
        int o = oc0 + oc;
        if (SHUF == 2) {
            // pixel_shuffle(r=2) fused into the store:
            // out[b, o>>2, 2h + ((o>>1)&1), 2w + (o&1)]
            int cc = o >> 2, r1 = (o >> 1) & 1, r2 = o & 1;
            size_t idx = ((size_t)(b * (COUT / 4) + cc) * (size_t)(2 * H) + (2 * py + r1))
                             * (size_t)(2 * W) + (2 * px + r2);
            out[idx] = v;
        } else {
            size_t idx = ((size_t)(b * COUT + o) * H + py) * (size_t)W + px;
            if (ACCUM) out[idx] += v;
            else       out[idx] = v;
        }
    }
}

// ---------------------------------------------------------------------------
// Fused: k_w2 conv (128->400) + kernel_normalize + dynamic 5x5 local conv
//        + pixel shuffle (s=4) + residual add.  One block per LR pixel.
// Never materializes the 105 MB up_kernel tensor.
// ---------------------------------------------------------------------------
__global__ __launch_bounds__(256) void fused_upsample_k(
    const float* __restrict__ k1,    // [B,128,128,128], already ReLU'd
    const float* __restrict__ w2,    // [400,128,3,3]
    const float* __restrict__ b2,    // [400]
    const float* __restrict__ x,     // [B,3,128,128]
    const float* __restrict__ resid, // [B,3,512,512]
    float* __restrict__ out)         // [B,3,512,512]
{
    const int pix = blockIdx.x;            // b*128*128 + h*128 + w
    const int b   = pix >> 14;
    const int rem = pix & 16383;
    const int h   = rem >> 7;
    const int w   = rem & 127;
    const int tid = threadIdx.x;

    __shared__ float k1t[128 * 9];   // [ic*9 + tap3]
    __shared__ float uk[400];        // up_kernel values, c = tap*16 + sidx
    __shared__ float mean_s[16];
    __shared__ float patch[3][25];   // 5x5 x-patch per channel

    // stage 3x3 neighborhood of k1 (zero-padded)
    for (int i = tid; i < 128 * 9; i += 256) {
        int ic = i / 9, t = i - ic * 9;
        int gy = h + t / 3 - 1, gx = w + t % 3 - 1;
        float v = 0.f;
        if (gy >= 0 && gy < 128 && gx >= 0 && gx < 128)
            v = k1[((size_t)(b * 128 + ic) * 128 + gy) * 128 + gx];
        k1t[i] = v;
    }
    // stage 5x5 x patch (zero-padded)
    for (int i = tid; i < 75; i += 256) {
        int c = i / 25, t = i - c * 25;
        int gy = h + t / 5 - 2, gx = w + t % 5 - 2;
        float v = 0.f;
        if (gy >= 0 && gy < 128 && gx >= 0 && gx < 128)
            v = x[((size_t)(b * 3 + c) * 128 + gy) * 128 + gx];
        patch[c][t] = v;
    }
    __syncthreads();

    // 400 up_kernel channels across 256 threads
    for (int oc = tid; oc < 400; oc += 256) {
        float a = b2[oc];
        const float* wp = w2 + (size_t)oc * 128 * 9;
#pragma unroll 4
        for (int ic = 0; ic < 128; ic++) {
#pragma unroll
            for (int t = 0; t < 9; t++)
                a = fmaf(k1t[ic * 9 + t], wp[ic * 9 + t], a);
        }
        uk[oc] = a;
    }
    __syncthreads();

    // kernel_normalize: zero-mean over the 25 taps per sidx, then +1/25
    if (tid < 16) {
        float m = 0.f;
        for (int tap = 0; tap < 25; tap++) m += uk[tap * 16 + tid];
        mean_s[tid] = m * (1.0f / 25.0f);
    }
    __syncthreads();

    // dynamic filter: 3 channels x 16 subpixels
    if (tid < 48) {
        int c = tid >> 4, sidx = tid & 15;
        float m = mean_s[sidx];
        float a = 0.f;
#pragma unroll
        for (int tap = 0; tap < 25; tap++)
            a = fmaf(patch[c][tap], uk[tap * 16 + sidx] - m + 0.04f, a);
        int s1 = sidx >> 2, s2 = sidx & 3;
        size_t oidx = ((size_t)(b * 3 + c) * 512 + (h * 4 + s1)) * 512 + (w * 4 + s2);
        out[oidx] = a + resid[oidx];
    }
}

// ---------------------------------------------------------------------------
extern "C" void kernel_launch(void* const* d_in, const int* in_sizes, int n_in,
                              void* d_out, int out_size, void* d_ws, size_t ws_size,
                              hipStream_t stream)
{
    const float* x      = (const float*)d_in[0];
    const float* w_in   = (const float*)d_in[1];
    const float* b_in   = (const float*)d_in[2];
    const float* res_w1 = (const float*)d_in[3];
    const float* res_b1 = (const float*)d_in[4];
    const float* res_w2 = (const float*)d_in[5];
    const float* res_b2 = (const float*)d_in[6];
    const float* r_w1   = (const float*)d_in[7];
    const float* r_b1   = (const float*)d_in[8];
    const float* r_w2   = (const float*)d_in[9];
    const float* r_b2   = (const float*)d_in[10];
    const float* r_w3   = (const float*)d_in[11];
    const float* r_b3   = (const float*)d_in[12];
    const float* k_w1   = (const float*)d_in[13];
    const float* k_b1   = (const float*)d_in[14];
    const float* k_w2   = (const float*)d_in[15];
    const float* k_b2   = (const float*)d_in[16];
    float* out = (float*)d_out;

    // workspace layout (fp32 elements)
    float* A = (float*)d_ws;          // f       [4,64,128,128]
    float* B = A + 4194304;           // h1      [4,64,128,128]
    float* C = B + 4194304;           // shuffled r1 [4,32,256,256]  (reused as k1 [4,128,128,128])
    float* D = C + 8388608;           // shuffled r2 [4,16,512,512]
    float* E = D + 16777216;          // residual_img [4,3,512,512]

    dim3 blk(256);

    // f = conv_in(x)
    conv3x3_k<3, 3, 64, 4, false, false, 0, false>
        <<<dim3(8, 8, 64), blk, 0, stream>>>(x, w_in, b_in, A, 128, 128);

    // 12 residual blocks: h = conv1(relu(f)); f += conv2(relu(h))
    for (int i = 0; i < 12; i++) {
        conv3x3_k<64, 8, 64, 4, true, false, 0, false>
            <<<dim3(8, 8, 64), blk, 0, stream>>>(A, res_w1 + (size_t)i * 64 * 64 * 9,
                                                 res_b1 + i * 64, B, 128, 128);
        conv3x3_k<64, 8, 64, 4, true, false, 0, true>
            <<<dim3(8, 8, 64), blk, 0, stream>>>(B, res_w2 + (size_t)i * 64 * 64 * 9,
                                                 res_b2 + i * 64, A, 128, 128);
    }

    // residual branch: relu(f) -> conv(64->128) -> relu -> PS2  => C [4,32,256,256]
    conv3x3_k<64, 8, 128, 4, true, true, 2, false>
        <<<dim3(8, 8, 128), blk, 0, stream>>>(A, r_w1, r_b1, C, 128, 128);
    // conv(32->64) -> relu -> PS2 => D [4,16,512,512]
    conv3x3_k<32, 8, 64, 4, false, true, 2, false>
        <<<dim3(16, 16, 64), blk, 0, stream>>>(C, r_w2, r_b2, D, 256, 256);
    // conv(16->3) => E residual_img [4,3,512,512]
    conv3x3_k<16, 8, 3, 3, false, false, 0, false>
        <<<dim3(32, 32, 4), blk, 0, stream>>>(D, r_w3, r_b3, E, 512, 512);

    // kernel branch stem: relu(f) -> conv(64->128) -> relu => C (as k1)
    conv3x3_k<64, 8, 128, 4, true, true, 0, false>
        <<<dim3(8, 8, 128), blk, 0, stream>>>(A, k_w1, k_b1, C, 128, 128);

    // fused k_w2 conv + normalize + dynamic local conv + PS4 + residual add
    fused_upsample_k<<<dim3(4 * 128 * 128), blk, 0, stream>>>(C, k_w2, k_b2, x, E, out);
}

// Round 2
// 4216.197 us; speedup vs baseline: 5.2150x; 5.2150x over previous
//
#include <hip/hip_runtime.h>

// ===========================================================================
// Tiled 3x3 SAME conv, NCHW fp32, register-tiled.
//  - 256 threads; spatial tile TSY x TSX; OCT output channels per block
//  - per-thread: COB(=4) ocs x 2x2 pixels = 16 accumulators
//  - per-ic 4x4 patch cached in registers (float2 LDS reads)
//  - weights in LDS k-major, oc-contiguous -> broadcast float4 reads
//  - optional ReLU in/out, pixel-shuffle(r=2) store, accumulate store
// ===========================================================================
template<int CIN, int ICB, int COUT, int OCT, int COB, int TSY, int TSX,
         bool RELU_IN, bool RELU_OUT, int SHUF, bool ACCUM>
__global__ __launch_bounds__(256) void conv3x3_v2(
    const float* __restrict__ in, const float* __restrict__ wgt,
    const float* __restrict__ bias, float* __restrict__ out,
    int H, int W)
{
    constexpr int NL  = OCT / COB;          // oc-lanes
    constexpr int PGX = TSX / 2;
    constexpr int PGY = TSY / 2;
    static_assert(NL * PGX * PGY == 256, "thread count");
    static_assert(COB == 4, "float4 weight read");
    static_assert(CIN % ICB == 0, "chunking");
    constexpr int HX = TSX + 2, HY = TSY + 2;
    constexpr int NK = ICB * 9;
    constexpr int NOCG = (COUT + OCT - 1) / OCT;

    const int tid  = threadIdx.x;
    const int lane = tid % NL;
    const int pg   = tid / NL;
    const int px2  = (pg % PGX) * 2;
    const int py2  = (pg / PGX) * 2;
    const int w0 = blockIdx.x * TSX;
    const int h0 = blockIdx.y * TSY;
    const int ocg = blockIdx.z % NOCG;
    const int b   = blockIdx.z / NOCG;
    const int ocb = ocg * OCT;
    const int oc0 = lane * COB;

    __shared__ float inT[ICB][HY][HX];
    __shared__ float wl[NK][OCT];

    float acc[COB][2][2];
#pragma unroll
    for (int o = 0; o < COB; o++) {
        float bv = (ocb + oc0 + o < COUT) ? bias[ocb + oc0 + o] : 0.f;
        acc[o][0][0] = bv; acc[o][0][1] = bv; acc[o][1][0] = bv; acc[o][1][1] = bv;
    }

    for (int ic0 = 0; ic0 < CIN; ic0 += ICB) {
        // ---- stage weights: global coalesced (runs of NK), LDS [k][oc]
        for (int i = tid; i < OCT * NK; i += 256) {
            int oc = i / NK, k = i - oc * NK;
            float v = 0.f;
            if (ocb + oc < COUT)
                v = wgt[(size_t)(ocb + oc) * (CIN * 9) + ic0 * 9 + k];
            wl[k][oc] = v;
        }
        // ---- stage input halo tile
        for (int i = tid; i < ICB * HY * HX; i += 256) {
            int ic = i / (HY * HX), r = i - ic * (HY * HX);
            int y = r / HX, x = r - y * HX;
            int gy = h0 + y - 1, gx = w0 + x - 1;
            float v = 0.f;
            if (gy >= 0 && gy < H && gx >= 0 && gx < W) {
                v = in[((size_t)(b * CIN + ic0 + ic) * H + gy) * W + gx];
                if (RELU_IN) v = fmaxf(v, 0.f);
            }
            inT[ic][y][x] = v;
        }
        __syncthreads();

#pragma unroll
        for (int ic = 0; ic < ICB; ic++) {
            float P[4][4];
#pragma unroll
            for (int r = 0; r < 4; r++) {
                float2 a = *reinterpret_cast<const float2*>(&inT[ic][py2 + r][px2]);
                float2 c = *reinterpret_cast<const float2*>(&inT[ic][py2 + r][px2 + 2]);
                P[r][0] = a.x; P[r][1] = a.y; P[r][2] = c.x; P[r][3] = c.y;
            }
#pragma unroll
            for (int t = 0; t < 9; t++) {
                const int dy = t / 3, dx = t % 3;
                float4 wv = *reinterpret_cast<const float4*>(&wl[ic * 9 + t][oc0]);
                float w_[4] = {wv.x, wv.y, wv.z, wv.w};
#pragma unroll
                for (int o = 0; o < COB; o++) {
                    acc[o][0][0] = fmaf(w_[o], P[dy][dx],         acc[o][0][0]);
                    acc[o][0][1] = fmaf(w_[o], P[dy][dx + 1],     acc[o][0][1]);
                    acc[o][1][0] = fmaf(w_[o], P[dy + 1][dx],     acc[o][1][0]);
                    acc[o][1][1] = fmaf(w_[o], P[dy + 1][dx + 1], acc[o][1][1]);
                }
            }
        }
        __syncthreads();
    }

#pragma unroll
    for (int o = 0; o < COB; o++) {
        int oc = ocb + oc0 + o;
        if (oc < COUT) {
#pragma unroll
            for (int py = 0; py < 2; py++) {
#pragma unroll
                for (int px = 0; px < 2; px++) {
                    float v = acc[o][py][px];
                    if (RELU_OUT) v = fmaxf(v, 0.f);
                    int hh = h0 + py2 + py, ww = w0 + px2 + px;
                    if (SHUF == 2) {
                        int cc = oc >> 2, r1 = (oc >> 1) & 1, r2 = oc & 1;
                        size_t idx = ((size_t)(b * (COUT / 4) + cc) * (size_t)(2 * H)
                                      + (2 * hh + r1)) * (size_t)(2 * W) + (2 * ww + r2);
                        out[idx] = v;
                    } else {
                        size_t idx = ((size_t)(b * COUT + oc) * H + hh) * (size_t)W + ww;
                        if (ACCUM) out[idx] += v;
                        else       out[idx] = v;
                    }
                }
            }
        }
    }
}

// ===========================================================================
// Implicit-GEMM for up_kernel: Ut[pix][400] = W2[400,1152] . im2col(k1)
// One batch per launch. Tile: 64 ocs x 8x8 pixels; thread: 4 oc x 2x2 pix.
// ===========================================================================
__global__ __launch_bounds__(256) void upgemm_k(
    const float* __restrict__ k1,   // [128,128,128] (one batch, ReLU'd)
    const float* __restrict__ w2,   // [400,128,3,3]
    const float* __restrict__ b2,   // [400]
    float* __restrict__ Ut)         // [16384][400]
{
    const int tid  = threadIdx.x;
    const int lane = tid & 15;          // oc-lane (4 ocs)
    const int pg   = tid >> 4;          // 16 pixel-groups of 2x2
    const int px2  = (pg & 3) * 2;
    const int py2  = (pg >> 2) * 2;
    const int ocb  = blockIdx.x * 64;   // 7 tiles (last masked, 400=6*64+16)
    const int pt   = blockIdx.y;        // 256 pixel tiles of 8x8
    const int ty0  = (pt >> 4) * 8;
    const int tx0  = (pt & 15) * 8;
    const int oc0  = lane * 4;

    __shared__ float k1t[8][10][10];
    __shared__ float w2l[72][65];       // stride-65 pad: conflict-free writes

    float acc[4][2][2];
#pragma unroll
    for (int o = 0; o < 4; o++) {
        float bv = (ocb + oc0 + o < 400) ? b2[ocb + oc0 + o] : 0.f;
        acc[o][0][0] = bv; acc[o][0][1] = bv; acc[o][1][0] = bv; acc[o][1][1] = bv;
    }

    for (int ic0 = 0; ic0 < 128; ic0 += 8) {
        // stage weights: coalesced global (runs of 72), LDS [k][oc] stride 65
        for (int i = tid; i < 64 * 72; i += 256) {
            int oc = i / 72, k = i - oc * 72;
            float v = 0.f;
            if (ocb + oc < 400)
                v = w2[(size_t)(ocb + oc) * 1152 + ic0 * 9 + k];
            w2l[k][oc] = v;
        }
        // stage k1 halo tile 10x10 x 8ic
        for (int i = tid; i < 800; i += 256) {
            int ic = i / 100, r = i - ic * 100;
            int y = r / 10, x = r - y * 10;
            int gy = ty0 + y - 1, gx = tx0 + x - 1;
            float v = 0.f;
            if (gy >= 0 && gy < 128 && gx >= 0 && gx < 128)
                v = k1[(size_t)(ic0 + ic) * 16384 + gy * 128 + gx];
            k1t[ic][y][x] = v;
        }
        __syncthreads();

#pragma unroll
        for (int ic = 0; ic < 8; ic++) {
            float P[4][4];
#pragma unroll
            for (int r = 0; r < 4; r++) {
                float2 a = *reinterpret_cast<const float2*>(&k1t[ic][py2 + r][px2]);
                float2 c = *reinterpret_cast<const float2*>(&k1t[ic][py2 + r][px2 + 2]);
                P[r][0] = a.x; P[r][1] = a.y; P[r][2] = c.x; P[r][3] = c.y;
            }
#pragma unroll
            for (int t = 0; t < 9; t++) {
                const int dy = t / 3, dx = t % 3;
                const float* wr = &w2l[ic * 9 + t][oc0];
                float w_[4] = {wr[0], wr[1], wr[2], wr[3]};
#pragma unroll
                for (int o = 0; o < 4; o++) {
                    acc[o][0][0] = fmaf(w_[o], P[dy][dx],         acc[o][0][0]);
                    acc[o][0][1] = fmaf(w_[o], P[dy][dx + 1],     acc[o][0][1]);
                    acc[o][1][0] = fmaf(w_[o], P[dy + 1][dx],     acc[o][1][0]);
                    acc[o][1][1] = fmaf(w_[o], P[dy + 1][dx + 1], acc[o][1][1]);
                }
            }
        }
        __syncthreads();
    }

    if (ocb + oc0 < 400) {
#pragma unroll
        for (int py = 0; py < 2; py++) {
#pragma unroll
            for (int px = 0; px < 2; px++) {
                int pix = (ty0 + py2 + py) * 128 + tx0 + px2 + px;
                float4 v = make_float4(acc[0][py][px], acc[1][py][px],
                                       acc[2][py][px], acc[3][py][px]);
                *reinterpret_cast<float4*>(&Ut[(size_t)pix * 400 + ocb + oc0]) = v;
            }
        }
    }
}

// ===========================================================================
// Normalize + dynamic 5x5 local conv + pixel-shuffle(4) + residual add.
// One batch per launch; block = 16 pixels x 16 subpixel-threads.
// ===========================================================================
__global__ __launch_bounds__(256) void filter_k(
    const float* __restrict__ Ut,    // [16384][400]
    const float* __restrict__ x,     // [3,128,128] (one batch)
    const float* __restrict__ resid, // [3,512,512] (one batch)
    float* __restrict__ out)         // [3,512,512] (one batch)
{
    const int tid = threadIdx.x;
    const int s   = tid & 15;    // subpixel 0..15
    const int pl  = tid >> 4;    // pixel lane 0..15
    const int pix0 = blockIdx.x * 16;
    const int y  = pix0 >> 7;
    const int x0 = pix0 & 127;

    __shared__ float xp[3][5][20];   // x patch rows y-2..y+2, cols x0-2..x0+17
    for (int i = tid; i < 300; i += 256) {
        int c = i / 100, r = i - c * 100;
        int dy = r / 20, dx = r - dy * 20;
        int gy = y + dy - 2, gx = x0 + dx - 2;
        float v = 0.f;
        if (gy >= 0 && gy < 128 && gx >= 0 && gx < 128)
            v = x[(size_t)c * 16384 + gy * 128 + gx];
        xp[c][dy][dx] = v;
    }
    __syncthreads();

    const int px = x0 + pl;
    const size_t ub = (size_t)(y * 128 + px) * 400;

    float u[25];
    float m = 0.f;
#pragma unroll
    for (int tap = 0; tap < 25; tap++) {
        u[tap] = Ut[ub + tap * 16 + s];
        m += u[tap];
    }
    m *= (1.0f / 25.0f);

    const int s1 = s >> 2, s2 = s & 3;
#pragma unroll
    for (int c = 0; c < 3; c++) {
        float a = 0.f;
#pragma unroll
        for (int tap = 0; tap < 25; tap++)
            a = fmaf(xp[c][tap / 5][pl + tap % 5], u[tap] - m + 0.04f, a);
        size_t oidx = ((size_t)c * 512 + (y * 4 + s1)) * 512 + (px * 4 + s2);
        out[oidx] = a + resid[oidx];
    }
}

// ===========================================================================
extern "C" void kernel_launch(void* const* d_in, const int* in_sizes, int n_in,
                              void* d_out, int out_size, void* d_ws, size_t ws_size,
                              hipStream_t stream)
{
    const float* x      = (const float*)d_in[0];
    const float* w_in   = (const float*)d_in[1];
    const float* b_in   = (const float*)d_in[2];
    const float* res_w1 = (const float*)d_in[3];
    const float* res_b1 = (const float*)d_in[4];
    const float* res_w2 = (const float*)d_in[5];
    const float* res_b2 = (const float*)d_in[6];
    const float* r_w1   = (const float*)d_in[7];
    const float* r_b1   = (const float*)d_in[8];
    const float* r_w2   = (const float*)d_in[9];
    const float* r_b2   = (const float*)d_in[10];
    const float* r_w3   = (const float*)d_in[11];
    const float* r_b3   = (const float*)d_in[12];
    const float* k_w1   = (const float*)d_in[13];
    const float* k_b1   = (const float*)d_in[14];
    const float* k_w2   = (const float*)d_in[15];
    const float* k_b2   = (const float*)d_in[16];
    float* out = (float*)d_out;

    // workspace (fp32 elements), total 36,700,160 elem = 146.8 MB (same as R0)
    float* E = (float*)d_ws;          // [4,3,512,512]      3,145,728
    float* C = E + 3145728;           // r1ps [4,32,256,256] / k1 [4,128,128,128]
    float* A = C + 8388608;           // f  [4,64,128,128]   4,194,304
    float* B = A + 4194304;           // h  [4,64,128,128]   4,194,304
    float* D = B + 4194304;           // r2ps [4,16,512,512] 16,777,216
    float* U = A;                     // per-batch Ut [16384][400] 6,553,600
                                      // (A+B dead before use; fits in 8,388,608)
    dim3 blk(256);

    // f = conv_in(x)
    conv3x3_v2<3, 3, 64, 16, 4, 16, 16, false, false, 0, false>
        <<<dim3(8, 8, 16), blk, 0, stream>>>(x, w_in, b_in, A, 128, 128);

    // 12 residual blocks
    for (int i = 0; i < 12; i++) {
        conv3x3_v2<64, 8, 64, 16, 4, 16, 16, true, false, 0, false>
            <<<dim3(8, 8, 16), blk, 0, stream>>>(A, res_w1 + (size_t)i * 36864,
                                                 res_b1 + i * 64, B, 128, 128);
        conv3x3_v2<64, 8, 64, 16, 4, 16, 16, true, false, 0, true>
            <<<dim3(8, 8, 16), blk, 0, stream>>>(B, res_w2 + (size_t)i * 36864,
                                                 res_b2 + i * 64, A, 128, 128);
    }

    // residual branch
    conv3x3_v2<64, 8, 128, 16, 4, 16, 16, true, true, 2, false>
        <<<dim3(8, 8, 32), blk, 0, stream>>>(A, r_w1, r_b1, C, 128, 128);
    conv3x3_v2<32, 8, 64, 16, 4, 16, 16, false, true, 2, false>
        <<<dim3(16, 16, 16), blk, 0, stream>>>(C, r_w2, r_b2, D, 256, 256);
    conv3x3_v2<16, 8, 3, 4, 4, 32, 32, false, false, 0, false>
        <<<dim3(16, 16, 4), blk, 0, stream>>>(D, r_w3, r_b3, E, 512, 512);

    // kernel branch stem: k1 = relu(conv(relu(f)))  -> C
    conv3x3_v2<64, 8, 128, 16, 4, 16, 16, true, true, 0, false>
        <<<dim3(8, 8, 32), blk, 0, stream>>>(A, k_w1, k_b1, C, 128, 128);

    // per-batch: up_kernel GEMM -> normalize+filter+PS4+residual
    for (int b = 0; b < 4; b++) {
        upgemm_k<<<dim3(7, 256), blk, 0, stream>>>(
            C + (size_t)b * 2097152, k_w2, k_b2, U);
        filter_k<<<dim3(1024), blk, 0, stream>>>(
            U, x + (size_t)b * 49152, E + (size_t)b * 786432,
            out + (size_t)b * 786432);
    }
}

// Round 4
// 931.170 us; speedup vs baseline: 23.6128x; 4.5278x over previous
//
#include <hip/hip_runtime.h>
#include <stdint.h>

typedef __attribute__((ext_vector_type(8))) __bf16 bf16x8;
typedef __attribute__((ext_vector_type(4))) float f32x4;

__device__ inline f32x4 MFMA(bf16x8 a, bf16x8 b, f32x4 c) {
    return __builtin_amdgcn_mfma_f32_16x16x32_bf16(a, b, c, 0, 0, 0);
}

// ===========================================================================
// Weight convert+transpose: fp32 [OC][IC][3][3] -> bf16 [9][OC][IC]
// ===========================================================================
struct WSeg { const float* src; int off, OC, IC; };
struct WTab { WSeg s[28]; };

__global__ __launch_bounds__(256) void wcvt_k(WTab tab, __bf16* dst) {
    const WSeg sg = tab.s[blockIdx.y];
    int n = sg.OC * sg.IC * 9;
    int e = blockIdx.x * 256 + threadIdx.x;
    if (e >= n) return;
    int ic9 = sg.IC * 9;
    int oc = e / ic9;
    int r  = e - oc * ic9;
    int ic = r / 9;
    int t  = r - ic * 9;
    dst[(size_t)sg.off + ((size_t)t * sg.OC + oc) * sg.IC + ic] = (__bf16)sg.src[e];
}

// ===========================================================================
// conv_in: 3->64 fp32 planar in, bf16 NHWC out. 16x16 tile, 1 px/thread.
// ===========================================================================
__global__ __launch_bounds__(256) void conv_in_k(
    const float* __restrict__ x, const float* __restrict__ w,
    const float* __restrict__ bias, __bf16* __restrict__ out)
{
    const int tid = threadIdx.x;
    const int ty = (blockIdx.x >> 3) * 16, tx = (blockIdx.x & 7) * 16;
    const int b = blockIdx.y;
    __shared__ float xs[3][18][18];
    __shared__ float wl[27][64];
    for (int i = tid; i < 27 * 64; i += 256) {
        int t = i >> 6, oc = i & 63;
        wl[t][oc] = w[oc * 27 + t];
    }
    for (int i = tid; i < 3 * 324; i += 256) {
        int c = i / 324, r = i - c * 324;
        int y = r / 18, xx = r - y * 18;
        int gy = ty + y - 1, gx = tx + xx - 1;
        float v = 0.f;
        if (gy >= 0 && gy < 128 && gx >= 0 && gx < 128)
            v = x[((size_t)(b * 3 + c) * 128 + gy) * 128 + gx];
        xs[c][y][xx] = v;
    }
    __syncthreads();
    const int py = tid >> 4, px = tid & 15;
    float acc[64];
#pragma unroll
    for (int o = 0; o < 64; o++) acc[o] = bias[o];
    for (int c = 0; c < 3; c++)
        for (int t = 0; t < 9; t++) {
            float p = xs[c][py + t / 3][px + t % 3];
            const float* wr = &wl[c * 9 + t][0];
#pragma unroll
            for (int o = 0; o < 64; o++) acc[o] = fmaf(p, wr[o], acc[o]);
        }
    __bf16* op = out + (((size_t)b * 16384) + (ty + py) * 128 + (tx + px)) * 64;
    for (int o = 0; o < 64; o += 8) {
        union { bf16x8 v; uint4 u; } pk;
#pragma unroll
        for (int j = 0; j < 8; j++) pk.v[j] = (__bf16)acc[o + j];
        *(uint4*)(op + o) = pk.u;
    }
}

// ===========================================================================
// MFMA 3x3 conv. NHWC bf16 in, wt [9][OCALL][CIN] bf16.
// 16x16 px tile, 4 waves; wave = M=MT*16 oc x N=64 px (4 rows of 16).
// STAGE: 0 = direct NHWC; 1 = PS2 gather from NHWC[4*CIN] at half res.
// OUTM: 0 = NHWC bf16 (RELU_OUT/ACCUM); 1 = planar f32 [OCALL][H*W].
// ===========================================================================
template<int CIN, int ICB, int MT, int STAGE, int OUTM,
         bool RELU_IN, bool RELU_OUT, bool ACCUM>
__global__ __launch_bounds__(256) void convm_k(
    const __bf16* __restrict__ in, const __bf16* __restrict__ wt,
    const float* __restrict__ bias, void* __restrict__ outv,
    int H, int W, int OCALL, int ocb0)
{
    constexpr int M = MT * 16;
    constexpr int CHUNKS = CIN / ICB;
    constexpr int GR = ICB / 8;               // 16B groups per row
    constexpr int GM = (GR >= 8 ? 7 : GR - 1);
    constexpr int KS = ICB / 32;

    const int tid = threadIdx.x;
    const int ntx = W >> 4;
    const int h0 = (blockIdx.x / ntx) << 4;
    const int w0 = (blockIdx.x % ntx) << 4;
    const int b = blockIdx.y;
    const int ocb = ocb0 + blockIdx.z * M;

    __shared__ __bf16 inT[324 * ICB];
    __shared__ __bf16 wT[9 * M * ICB];

    const int lane = tid & 63;
    const int wv = tid >> 6;
    const int cl = lane & 15;     // col (pixel-x / oc-low for A rows)
    const int kg = lane >> 4;     // k-group
    const int row0 = wv << 2;

    f32x4 acc[MT][4];
#pragma unroll
    for (int m = 0; m < MT; m++) {
        f32x4 bv;
#pragma unroll
        for (int j = 0; j < 4; j++) bv[j] = bias[ocb + m * 16 + kg * 4 + j];
#pragma unroll
        for (int n = 0; n < 4; n++) acc[m][n] = bv;
    }

    for (int c = 0; c < CHUNKS; c++) {
        if (c) __syncthreads();
        // ---- stage input halo tile (18x18) for this ic chunk
        if (STAGE == 0) {
            for (int i = tid; i < 324 * GR; i += 256) {
                int pix = i / GR, g = i - pix * GR;
                int y = pix / 18, xx = pix - y * 18;
                int gy = h0 + y - 1, gx = w0 + xx - 1;
                union { uint4 u; bf16x8 v; unsigned short us[8]; } d;
                d.u = make_uint4(0u, 0u, 0u, 0u);
                if (gy >= 0 && gy < H && gx >= 0 && gx < W) {
                    d.u = *(const uint4*)(in + (((size_t)(b * H + gy)) * W + gx) * CIN
                                          + c * ICB + g * 8);
                    if (RELU_IN) {
#pragma unroll
                        for (int j = 0; j < 8; j++)
                            if (d.us[j] & 0x8000u) d.us[j] = 0;
                    }
                }
                int sg = (g & ~GM) | ((g ^ pix) & GM);
                *(bf16x8*)(inT + pix * ICB + sg * 8) = d.v;
            }
        } else {
            const int SRCC = 4 * CIN;
            for (int i = tid; i < 324 * ICB; i += 256) {
                int pix = i / ICB, e = i - pix * ICB;
                int y = pix / 18, xx = pix - y * 18;
                int gy = h0 + y - 1, gx = w0 + xx - 1;
                __bf16 v = (__bf16)0.f;
                if (gy >= 0 && gy < H && gx >= 0 && gx < W) {
                    int sub = ((gy & 1) << 1) | (gx & 1);
                    v = in[(((size_t)(b * (H >> 1) + (gy >> 1))) * (W >> 1) + (gx >> 1))
                               * SRCC + e * 4 + sub];
                }
                int g = e >> 3;
                int sg = (g & ~GM) | ((g ^ pix) & GM);
                inT[pix * ICB + sg * 8 + (e & 7)] = v;
            }
        }
        // ---- stage weights for this chunk: [t][oc][ic] swizzled by oc
        for (int i = tid; i < 9 * M * GR; i += 256) {
            int t = i / (M * GR), r = i - t * (M * GR);
            int oc = r / GR, g = r - oc * GR;
            union { uint4 u; bf16x8 v; } d;
            d.u = *(const uint4*)(wt + ((size_t)t * OCALL + ocb + oc) * CIN
                                  + c * ICB + g * 8);
            int sg = (g & ~GM) | ((g ^ oc) & GM);
            *(bf16x8*)(wT + ((t * M) + oc) * ICB + sg * 8) = d.v;
        }
        __syncthreads();

        // ---- 9 taps x K-steps of MFMA
#pragma unroll
        for (int t = 0; t < 9; t++) {
            const int dy = t / 3, dx = t % 3;
            const __bf16* wb = wT + t * M * ICB;
#pragma unroll
            for (int ks = 0; ks < KS; ks++) {
                bf16x8 af[MT], bfr[4];
#pragma unroll
                for (int m = 0; m < MT; m++) {
                    int oc = m * 16 + cl;
                    int g = ks * 4 + kg;
                    int sg = (g & ~GM) | ((g ^ oc) & GM);
                    af[m] = *(const bf16x8*)(wb + oc * ICB + sg * 8);
                }
#pragma unroll
                for (int n = 0; n < 4; n++) {
                    int pix = (row0 + n + dy) * 18 + cl + dx;
                    int g = ks * 4 + kg;
                    int sg = (g & ~GM) | ((g ^ pix) & GM);
                    bfr[n] = *(const bf16x8*)(inT + pix * ICB + sg * 8);
                }
#pragma unroll
                for (int m = 0; m < MT; m++)
#pragma unroll
                    for (int n = 0; n < 4; n++)
                        acc[m][n] = MFMA(af[m], bfr[n], acc[m][n]);
            }
        }
    }

    // ---- epilogue. C frag: col(pixel-x)=cl, oc = m*16 + kg*4 + j
    if (OUTM == 0) {
        __bf16* outp = (__bf16*)outv;
#pragma unroll
        for (int m = 0; m < MT; m++) {
            int oc = ocb + m * 16 + kg * 4;
#pragma unroll
            for (int n = 0; n < 4; n++) {
                __bf16* op = outp + (((size_t)(b * H + h0 + row0 + n)) * W + (w0 + cl))
                                 * OCALL + oc;
                f32x4 v = acc[m][n];
                if (ACCUM) {
                    union { uint2 u; __bf16 hx[4]; } old;
                    old.u = *(const uint2*)op;
#pragma unroll
                    for (int j = 0; j < 4; j++) v[j] += (float)old.hx[j];
                }
                union { uint2 u; __bf16 hx[4]; } pk;
#pragma unroll
                for (int j = 0; j < 4; j++) {
                    float f = v[j];
                    if (RELU_OUT) f = fmaxf(f, 0.f);
                    pk.hx[j] = (__bf16)f;
                }
                *(uint2*)op = pk.u;
            }
        }
    } else {
        float* outp = (float*)outv;
        const int HW = H * W;
#pragma unroll
        for (int m = 0; m < MT; m++) {
            int oc = ocb + m * 16 + kg * 4;
#pragma unroll
            for (int n = 0; n < 4; n++) {
                int pix = (h0 + row0 + n) * W + w0 + cl;
#pragma unroll
                for (int j = 0; j < 4; j++)
                    outp[(size_t)(oc + j) * HW + pix] = acc[m][n][j];
            }
        }
    }
}

// ===========================================================================
// r_w3: 16->3 vector conv @512^2, PS2-gather input from r2 NHWC[64] @256^2.
// ===========================================================================
__global__ __launch_bounds__(256) void rw3_k(
    const __bf16* __restrict__ r2, const float* __restrict__ w,
    const float* __restrict__ bias, float* __restrict__ E)
{
    const int tid = threadIdx.x;
    const int ty = (blockIdx.x >> 5) * 16, tx = (blockIdx.x & 31) * 16;
    const int b = blockIdx.y;
    __shared__ __bf16 xs[324 * 16];
    __shared__ float wl[432];
    for (int i = tid; i < 432; i += 256) wl[i] = w[i];
    for (int i = tid; i < 324 * 16; i += 256) {
        int pix = i >> 4, e = i & 15;
        int y = pix / 18, xx = pix - y * 18;
        int gy = ty + y - 1, gx = tx + xx - 1;
        __bf16 v = (__bf16)0.f;
        if (gy >= 0 && gy < 512 && gx >= 0 && gx < 512) {
            int sub = ((gy & 1) << 1) | (gx & 1);
            v = r2[(((size_t)(b * 256 + (gy >> 1))) * 256 + (gx >> 1)) * 64 + e * 4 + sub];
        }
        xs[pix * 16 + e] = v;
    }
    __syncthreads();
    const int py = tid >> 4, px = tid & 15;
    float a0 = bias[0], a1 = bias[1], a2 = bias[2];
    for (int t = 0; t < 9; t++) {
        const __bf16* xp = xs + ((py + t / 3) * 18 + px + t % 3) * 16;
#pragma unroll
        for (int ic = 0; ic < 16; ic++) {
            float p = (float)xp[ic];
            a0 = fmaf(p, wl[ic * 9 + t], a0);
            a1 = fmaf(p, wl[144 + ic * 9 + t], a1);
            a2 = fmaf(p, wl[288 + ic * 9 + t], a2);
        }
    }
    size_t o = (size_t)b * 3 * 262144 + (size_t)(ty + py) * 512 + (tx + px);
    E[o] = a0; E[o + 262144] = a1; E[o + 524288] = a2;
}

// ===========================================================================
// filter: normalize + dynamic 5x5 + PS4 + residual. Ut planar [400][16384].
// Batch offsets for x/E/out all applied INTERNALLY via b.
// ===========================================================================
__global__ __launch_bounds__(256) void filter_k(
    const float* __restrict__ Ut, const float* __restrict__ x,
    const float* __restrict__ E, float* __restrict__ out, int b)
{
    const int tid = threadIdx.x;
    const int s  = tid >> 4;    // subpixel 0..15
    const int pl = tid & 15;    // pixel lane
    const int pix0 = blockIdx.x * 16;
    const int y  = pix0 >> 7;
    const int x0 = pix0 & 127;

    __shared__ float xp[3][5][20];
    __shared__ float vs[3][16][16];   // [c][s][pl]
    for (int i = tid; i < 300; i += 256) {
        int c = i / 100, r = i - c * 100;
        int dy = r / 20, dx = r - dy * 20;
        int gy = y + dy - 2, gx = x0 + dx - 2;
        float v = 0.f;
        if (gy >= 0 && gy < 128 && gx >= 0 && gx < 128)
            v = x[((size_t)(b * 3 + c) * 128 + gy) * 128 + gx];
        xp[c][dy][dx] = v;
    }
    __syncthreads();

    const int px = x0 + pl;
    const float* ub = Ut + y * 128 + px;
    float u[25], m = 0.f;
#pragma unroll
    for (int tap = 0; tap < 25; tap++) {
        u[tap] = ub[(size_t)(tap * 16 + s) * 16384];
        m += u[tap];
    }
    m *= 0.04f;
#pragma unroll
    for (int c = 0; c < 3; c++) {
        float a = 0.f;
#pragma unroll
        for (int tap = 0; tap < 25; tap++)
            a = fmaf(xp[c][tap / 5][pl + tap % 5], u[tap] - m + 0.04f, a);
        vs[c][s][pl] = a;
    }
    __syncthreads();

    const size_t Eb = (size_t)b * 3 * 262144;
    for (int i = tid; i < 768; i += 256) {
        int c = i >> 8, r = i & 255;
        int s1 = r >> 6, cc = r & 63;
        float v = vs[c][s1 * 4 + (cc & 3)][cc >> 2];
        size_t o = Eb + (size_t)c * 262144 + (size_t)(y * 4 + s1) * 512 + x0 * 4 + cc;
        out[o] = v + E[o];
    }
}

// ===========================================================================
extern "C" void kernel_launch(void* const* d_in, const int* in_sizes, int n_in,
                              void* d_out, int out_size, void* d_ws, size_t ws_size,
                              hipStream_t stream)
{
    const float* x      = (const float*)d_in[0];
    const float* w_in   = (const float*)d_in[1];
    const float* b_in   = (const float*)d_in[2];
    const float* res_w1 = (const float*)d_in[3];
    const float* res_b1 = (const float*)d_in[4];
    const float* res_w2 = (const float*)d_in[5];
    const float* res_b2 = (const float*)d_in[6];
    const float* r_w1   = (const float*)d_in[7];
    const float* r_b1   = (const float*)d_in[8];
    const float* r_w2   = (const float*)d_in[9];
    const float* r_b2   = (const float*)d_in[10];
    const float* r_w3   = (const float*)d_in[11];
    const float* r_b3   = (const float*)d_in[12];
    const float* k_w1   = (const float*)d_in[13];
    const float* k_b1   = (const float*)d_in[14];
    const float* k_w2   = (const float*)d_in[15];
    const float* k_b2   = (const float*)d_in[16];
    float* out = (float*)d_out;

    char* ws = (char*)d_ws;
    __bf16* WT = (__bf16*)ws;                                   // 1,511,424 bf16
    __bf16* F  = (__bf16*)(ws + 3145728);                       // [4,128,128,64]
    __bf16* Hb = (__bf16*)(ws + 11534336);                      // [4,128,128,64]
    __bf16* R1 = (__bf16*)(ws + 19922944);                      // [4,128,128,128]
    __bf16* R2 = (__bf16*)(ws + 36700160);                      // [4,256,256,64]
    __bf16* K1 = (__bf16*)(ws + 70254592);                      // [4,128,128,128]
    float*  E  = (float*) (ws + 87031808);                      // [4,3,512,512]
    float*  Ut = (float*) (ws + 99614720);                      // [400][16384]

    // WT offsets (bf16 elems)
    const int oRes1 = 0, oRes2 = 442368, oRw1 = 884736, oKw1 = 958464,
              oRw2 = 1032192, oKw2 = 1050624;

    WTab tab;
    for (int i = 0; i < 12; i++)
        tab.s[i]      = { res_w1 + (size_t)i * 36864, oRes1 + i * 36864, 64, 64 };
    for (int i = 0; i < 12; i++)
        tab.s[12 + i] = { res_w2 + (size_t)i * 36864, oRes2 + i * 36864, 64, 64 };
    tab.s[24] = { r_w1, oRw1, 128, 64 };
    tab.s[25] = { k_w1, oKw1, 128, 64 };
    tab.s[26] = { r_w2, oRw2, 64, 32 };
    tab.s[27] = { k_w2, oKw2, 400, 128 };

    dim3 blk(256);
    wcvt_k<<<dim3(1800, 28), blk, 0, stream>>>(tab, WT);

    conv_in_k<<<dim3(64, 4), blk, 0, stream>>>(x, w_in, b_in, F);

    for (int i = 0; i < 12; i++) {
        convm_k<64, 64, 4, 0, 0, true, true, false><<<dim3(64, 4, 1), blk, 0, stream>>>(
            F, WT + oRes1 + i * 36864, res_b1 + i * 64, Hb, 128, 128, 64, 0);
        convm_k<64, 64, 4, 0, 0, false, false, true><<<dim3(64, 4, 1), blk, 0, stream>>>(
            Hb, WT + oRes2 + i * 36864, res_b2 + i * 64, F, 128, 128, 64, 0);
    }

    // residual branch
    convm_k<64, 64, 4, 0, 0, true, true, false><<<dim3(64, 4, 2), blk, 0, stream>>>(
        F, WT + oRw1, r_b1, R1, 128, 128, 128, 0);
    convm_k<32, 32, 4, 1, 0, false, true, false><<<dim3(256, 4, 1), blk, 0, stream>>>(
        R1, WT + oRw2, r_b2, R2, 256, 256, 64, 0);
    rw3_k<<<dim3(1024, 4), blk, 0, stream>>>(R2, r_w3, r_b3, E);

    // kernel branch stem
    convm_k<64, 64, 4, 0, 0, true, true, false><<<dim3(64, 4, 2), blk, 0, stream>>>(
        F, WT + oKw1, k_b1, K1, 128, 128, 128, 0);

    for (int b = 0; b < 4; b++) {
        const __bf16* k1b = K1 + (size_t)b * 2097152;
        convm_k<128, 64, 4, 0, 1, false, false, false><<<dim3(64, 1, 6), blk, 0, stream>>>(
            k1b, WT + oKw2, k_b2, Ut, 128, 128, 400, 0);
        convm_k<128, 64, 1, 0, 1, false, false, false><<<dim3(64, 1, 1), blk, 0, stream>>>(
            k1b, WT + oKw2, k_b2, Ut, 128, 128, 400, 384);
        filter_k<<<dim3(1024), blk, 0, stream>>>(Ut, x, E, out, b);
    }
}

// Round 5
// 669.344 us; speedup vs baseline: 32.8493x; 1.3912x over previous
//
#include <hip/hip_runtime.h>
#include <stdint.h>

typedef __attribute__((ext_vector_type(8))) __bf16 bf16x8;
typedef __attribute__((ext_vector_type(4))) float f32x4;

__device__ inline f32x4 MFMA(bf16x8 a, bf16x8 b, f32x4 c) {
    return __builtin_amdgcn_mfma_f32_16x16x32_bf16(a, b, c, 0, 0, 0);
}

// ===========================================================================
// Weight convert+transpose: fp32 [OC][IC][3][3] -> bf16 [9][OC][IC]
// ===========================================================================
struct WSeg { const float* src; int off, OC, IC; };
struct WTab { WSeg s[28]; };

__global__ __launch_bounds__(256) void wcvt_k(WTab tab, __bf16* dst, int seg0) {
    const WSeg sg = tab.s[seg0 + blockIdx.y];
    int n = sg.OC * sg.IC * 9;
    int e = blockIdx.x * 256 + threadIdx.x;
    if (e >= n) return;
    int ic9 = sg.IC * 9;
    int oc = e / ic9;
    int r  = e - oc * ic9;
    int ic = r / 9;
    int t  = r - ic * 9;
    dst[(size_t)sg.off + ((size_t)t * sg.OC + oc) * sg.IC + ic] = (__bf16)sg.src[e];
}

// ===========================================================================
// conv_in: 3->64 fp32 planar in, bf16 NHWC out. 16x16 tile, 1 px/thread.
// ===========================================================================
__global__ __launch_bounds__(256) void conv_in_k(
    const float* __restrict__ x, const float* __restrict__ w,
    const float* __restrict__ bias, __bf16* __restrict__ out)
{
    const int tid = threadIdx.x;
    const int ty = (blockIdx.x >> 3) * 16, tx = (blockIdx.x & 7) * 16;
    const int b = blockIdx.y;
    __shared__ float xs[3][18][18];
    __shared__ float wl[27][64];
    for (int i = tid; i < 27 * 64; i += 256) {
        int t = i >> 6, oc = i & 63;
        wl[t][oc] = w[oc * 27 + t];
    }
    for (int i = tid; i < 3 * 324; i += 256) {
        int c = i / 324, r = i - c * 324;
        int y = r / 18, xx = r - y * 18;
        int gy = ty + y - 1, gx = tx + xx - 1;
        float v = 0.f;
        if (gy >= 0 && gy < 128 && gx >= 0 && gx < 128)
            v = x[((size_t)(b * 3 + c) * 128 + gy) * 128 + gx];
        xs[c][y][xx] = v;
    }
    __syncthreads();
    const int py = tid >> 4, px = tid & 15;
    float acc[64];
#pragma unroll
    for (int o = 0; o < 64; o++) acc[o] = bias[o];
    for (int c = 0; c < 3; c++)
        for (int t = 0; t < 9; t++) {
            float p = xs[c][py + t / 3][px + t % 3];
            const float* wr = &wl[c * 9 + t][0];
#pragma unroll
            for (int o = 0; o < 64; o++) acc[o] = fmaf(p, wr[o], acc[o]);
        }
    __bf16* op = out + (((size_t)b * 16384) + (ty + py) * 128 + (tx + px)) * 64;
    for (int o = 0; o < 64; o += 8) {
        union { bf16x8 v; uint4 u; } pk;
#pragma unroll
        for (int j = 0; j < 8; j++) pk.v[j] = (__bf16)acc[o + j];
        *(uint4*)(op + o) = pk.u;
    }
}

// ===========================================================================
// MFMA 3x3 conv. NHWC bf16 in, wt [9][OCALL][CIN] bf16.
// 16x16 px tile, 4 waves; wave = M=MT*16 oc x N=64 px (4 rows of 16).
// STAGE: 0 = direct NHWC; 1 = PS2 gather from NHWC[4*CIN] at half res.
// OUTM: 0 = NHWC bf16; 1 = planar bf16 [b][OCALL][H*W];
//       2 = PS2 sub-plane planar bf16 [b][sub][OCALL/4][H][W].
// OCGUARD: mask ocs >= OCALL (for 400-channel GEMM tail).
// ===========================================================================
template<int CIN, int ICB, int MT, int STAGE, int OUTM,
         bool RELU_IN, bool RELU_OUT, bool ACCUM, bool OCGUARD>
__global__ __launch_bounds__(256) void convm_k(
    const __bf16* __restrict__ in, const __bf16* __restrict__ wt,
    const float* __restrict__ bias, void* __restrict__ outv,
    int H, int W, int OCALL, int ocb0)
{
    constexpr int M = MT * 16;
    constexpr int CHUNKS = CIN / ICB;
    constexpr int GR = ICB / 8;               // 16B groups per row
    constexpr int GM = (GR >= 8 ? 7 : GR - 1);
    constexpr int KS = ICB / 32;

    const int tid = threadIdx.x;
    const int ntx = W >> 4;
    const int h0 = (blockIdx.x / ntx) << 4;
    const int w0 = (blockIdx.x % ntx) << 4;
    const int b = blockIdx.y;
    const int ocb = ocb0 + blockIdx.z * M;

    __shared__ __bf16 inT[324 * ICB];
    __shared__ __bf16 wT[9 * M * ICB];

    const int lane = tid & 63;
    const int wv = tid >> 6;
    const int cl = lane & 15;     // col (pixel-x / oc-low for A rows)
    const int kg = lane >> 4;     // k-group
    const int row0 = wv << 2;

    f32x4 acc[MT][4];
#pragma unroll
    for (int m = 0; m < MT; m++) {
        f32x4 bv;
#pragma unroll
        for (int j = 0; j < 4; j++) {
            int o = ocb + m * 16 + kg * 4 + j;
            bv[j] = (!OCGUARD || o < OCALL) ? bias[o] : 0.f;
        }
#pragma unroll
        for (int n = 0; n < 4; n++) acc[m][n] = bv;
    }

    for (int c = 0; c < CHUNKS; c++) {
        if (c) __syncthreads();
        // ---- stage input halo tile (18x18) for this ic chunk
        if (STAGE == 0) {
            for (int i = tid; i < 324 * GR; i += 256) {
                int pix = i / GR, g = i - pix * GR;
                int y = pix / 18, xx = pix - y * 18;
                int gy = h0 + y - 1, gx = w0 + xx - 1;
                union { uint4 u; bf16x8 v; unsigned short us[8]; } d;
                d.u = make_uint4(0u, 0u, 0u, 0u);
                if (gy >= 0 && gy < H && gx >= 0 && gx < W) {
                    d.u = *(const uint4*)(in + (((size_t)(b * H + gy)) * W + gx) * CIN
                                          + c * ICB + g * 8);
                    if (RELU_IN) {
#pragma unroll
                        for (int j = 0; j < 8; j++)
                            if (d.us[j] & 0x8000u) d.us[j] = 0;
                    }
                }
                int sg = (g & ~GM) | ((g ^ pix) & GM);
                *(bf16x8*)(inT + pix * ICB + sg * 8) = d.v;
            }
        } else {
            const int SRCC = 4 * CIN;
            for (int i = tid; i < 324 * ICB; i += 256) {
                int pix = i / ICB, e = i - pix * ICB;
                int y = pix / 18, xx = pix - y * 18;
                int gy = h0 + y - 1, gx = w0 + xx - 1;
                __bf16 v = (__bf16)0.f;
                if (gy >= 0 && gy < H && gx >= 0 && gx < W) {
                    int sub = ((gy & 1) << 1) | (gx & 1);
                    v = in[(((size_t)(b * (H >> 1) + (gy >> 1))) * (W >> 1) + (gx >> 1))
                               * SRCC + e * 4 + sub];
                }
                int g = e >> 3;
                int sg = (g & ~GM) | ((g ^ pix) & GM);
                inT[pix * ICB + sg * 8 + (e & 7)] = v;
            }
        }
        // ---- stage weights for this chunk: [t][oc][ic] swizzled by oc
        for (int i = tid; i < 9 * M * GR; i += 256) {
            int t = i / (M * GR), r = i - t * (M * GR);
            int oc = r / GR, g = r - oc * GR;
            int ocr = ocb + oc;
            if (OCGUARD) ocr = (ocr < OCALL) ? ocr : (OCALL - 1);
            union { uint4 u; bf16x8 v; } d;
            d.u = *(const uint4*)(wt + ((size_t)t * OCALL + ocr) * CIN
                                  + c * ICB + g * 8);
            int sg = (g & ~GM) | ((g ^ oc) & GM);
            *(bf16x8*)(wT + ((t * M) + oc) * ICB + sg * 8) = d.v;
        }
        __syncthreads();

        // ---- 9 taps x K-steps of MFMA
#pragma unroll
        for (int t = 0; t < 9; t++) {
            const int dy = t / 3, dx = t % 3;
            const __bf16* wb = wT + t * M * ICB;
#pragma unroll
            for (int ks = 0; ks < KS; ks++) {
                bf16x8 af[MT], bfr[4];
#pragma unroll
                for (int m = 0; m < MT; m++) {
                    int oc = m * 16 + cl;
                    int g = ks * 4 + kg;
                    int sg = (g & ~GM) | ((g ^ oc) & GM);
                    af[m] = *(const bf16x8*)(wb + oc * ICB + sg * 8);
                }
#pragma unroll
                for (int n = 0; n < 4; n++) {
                    int pix = (row0 + n + dy) * 18 + cl + dx;
                    int g = ks * 4 + kg;
                    int sg = (g & ~GM) | ((g ^ pix) & GM);
                    bfr[n] = *(const bf16x8*)(inT + pix * ICB + sg * 8);
                }
#pragma unroll
                for (int m = 0; m < MT; m++)
#pragma unroll
                    for (int n = 0; n < 4; n++)
                        acc[m][n] = MFMA(af[m], bfr[n], acc[m][n]);
            }
        }
    }

    // ---- epilogue. C frag: col(pixel-x)=cl, oc = m*16 + kg*4 + j
    if (OUTM == 0) {
        __bf16* outp = (__bf16*)outv;
#pragma unroll
        for (int m = 0; m < MT; m++) {
            int oc = ocb + m * 16 + kg * 4;
#pragma unroll
            for (int n = 0; n < 4; n++) {
                __bf16* op = outp + (((size_t)(b * H + h0 + row0 + n)) * W + (w0 + cl))
                                 * OCALL + oc;
                f32x4 v = acc[m][n];
                if (ACCUM) {
                    union { uint2 u; __bf16 hx[4]; } old;
                    old.u = *(const uint2*)op;
#pragma unroll
                    for (int j = 0; j < 4; j++) v[j] += (float)old.hx[j];
                }
                union { uint2 u; __bf16 hx[4]; } pk;
#pragma unroll
                for (int j = 0; j < 4; j++) {
                    float f = v[j];
                    if (RELU_OUT) f = fmaxf(f, 0.f);
                    pk.hx[j] = (__bf16)f;
                }
                *(uint2*)op = pk.u;
            }
        }
    } else if (OUTM == 1) {
        __bf16* outp = (__bf16*)outv;
        const int HW = H * W;
#pragma unroll
        for (int m = 0; m < MT; m++) {
            int oc = ocb + m * 16 + kg * 4;
#pragma unroll
            for (int n = 0; n < 4; n++) {
                int pix = (h0 + row0 + n) * W + w0 + cl;
#pragma unroll
                for (int j = 0; j < 4; j++) {
                    if (!OCGUARD || oc + j < OCALL)
                        outp[(size_t)(b * OCALL + oc + j) * HW + pix]
                            = (__bf16)acc[m][n][j];
                }
            }
        }
    } else {   // OUTM == 2: PS2 sub-plane planar [b][sub][OCALL/4][H][W]
        __bf16* outp = (__bf16*)outv;
        const int HW = H * W;
        const int CP = OCALL >> 2;
#pragma unroll
        for (int m = 0; m < MT; m++) {
            int oc = ocb + m * 16 + kg * 4;
#pragma unroll
            for (int n = 0; n < 4; n++) {
                int pix = (h0 + row0 + n) * W + w0 + cl;
#pragma unroll
                for (int j = 0; j < 4; j++) {
                    int o = oc + j;
                    float f = acc[m][n][j];
                    if (RELU_OUT) f = fmaxf(f, 0.f);
                    outp[((size_t)((b * 4 + (o & 3)) * CP + (o >> 2))) * HW + pix]
                        = (__bf16)f;
                }
            }
        }
    }
}

// ===========================================================================
// r_w3: 16->3 conv @512^2 from PS2 sub-plane r2 [b][4][16][256][256].
// Block: 16x16 LR tile -> 32x32 HR out. Thread: 4 consecutive HR px.
// ===========================================================================
__global__ __launch_bounds__(256) void rw3_k(
    const __bf16* __restrict__ r2p, const float* __restrict__ w,
    const float* __restrict__ bias, float* __restrict__ E)
{
    const int tid = threadIdx.x;
    const int tY = (blockIdx.x >> 4) * 16;
    const int tX = (blockIdx.x & 15) * 16;
    const int b = blockIdx.y;

    __shared__ __bf16 xs[4][18][18][16];   // [sub][y][x][ch]
    __shared__ float wl[3][9][16];
    for (int i = tid; i < 432; i += 256) {
        int oc = i / 144, r = i - oc * 144;
        int t = r >> 4, e = r & 15;
        wl[oc][t][e] = w[(oc * 16 + e) * 9 + t];
    }
    // stage: i = ((sub*16+e)*18 + y)*18 + x  (x innermost -> coalesced reads)
    for (int i = tid; i < 4 * 16 * 18 * 18; i += 256) {
        int x = i % 18; int r = i / 18;
        int y = r % 18; r /= 18;
        int e = r & 15, sub = r >> 4;
        int gy = tY + y - 1, gx = tX + x - 1;
        __bf16 v = (__bf16)0.f;
        if (gy >= 0 && gy < 256 && gx >= 0 && gx < 256)
            v = r2p[(((size_t)(b * 4 + sub) * 16 + e) << 16) + (gy << 8) + gx];
        xs[sub][y][x][e] = v;
    }
    __syncthreads();

    const int hyl = tid >> 3;           // 0..31
    const int hx0 = (tid & 7) * 4;      // 0..28
    float acc[3][4];
#pragma unroll
    for (int oc = 0; oc < 3; oc++)
#pragma unroll
        for (int p = 0; p < 4; p++) acc[oc][p] = bias[oc];

#pragma unroll
    for (int dy = 0; dy < 3; dy++) {
        int hy = hyl + dy - 1;
        int ys = (hy >> 1) + 1;
        int suby = (hy & 1) << 1;
#pragma unroll
        for (int dx = 0; dx < 3; dx++) {
            const int t = dy * 3 + dx;
#pragma unroll
            for (int p = 0; p < 4; p++) {
                int hx = hx0 + p + dx - 1;
                int sub = suby | (hx & 1);
                int xsx = (hx >> 1) + 1;
                const __bf16* bp = &xs[sub][ys][xsx][0];
                bf16x8 v0 = *(const bf16x8*)bp;
                bf16x8 v1 = *(const bf16x8*)(bp + 8);
#pragma unroll
                for (int e = 0; e < 8; e++) {
                    float f0 = (float)v0[e], f1 = (float)v1[e];
                    acc[0][p] = fmaf(f0, wl[0][t][e], acc[0][p]);
                    acc[1][p] = fmaf(f0, wl[1][t][e], acc[1][p]);
                    acc[2][p] = fmaf(f0, wl[2][t][e], acc[2][p]);
                    acc[0][p] = fmaf(f1, wl[0][t][e + 8], acc[0][p]);
                    acc[1][p] = fmaf(f1, wl[1][t][e + 8], acc[1][p]);
                    acc[2][p] = fmaf(f1, wl[2][t][e + 8], acc[2][p]);
                }
            }
        }
    }
    const int HY = tY * 2 + hyl, HX = tX * 2 + hx0;
#pragma unroll
    for (int oc = 0; oc < 3; oc++) {
        float4 v = make_float4(acc[oc][0], acc[oc][1], acc[oc][2], acc[oc][3]);
        *(float4*)&E[(((size_t)(b * 3 + oc)) << 18) + HY * 512 + HX] = v;
    }
}

// ===========================================================================
// filter: normalize + dynamic 5x5 + PS4 + residual. Ut bf16 [b][400][16384].
// ===========================================================================
__global__ __launch_bounds__(256) void filter_k(
    const __bf16* __restrict__ Ut, const float* __restrict__ x,
    const float* __restrict__ E, float* __restrict__ out)
{
    const int tid = threadIdx.x;
    const int s  = tid >> 4;    // subpixel 0..15
    const int pl = tid & 15;    // pixel lane
    const int b  = blockIdx.y;
    const int pix0 = blockIdx.x * 16;
    const int y  = pix0 >> 7;
    const int x0 = pix0 & 127;

    __shared__ float xp[3][5][20];
    __shared__ float vs[3][16][16];   // [c][s][pl]
    for (int i = tid; i < 300; i += 256) {
        int c = i / 100, r = i - c * 100;
        int dy = r / 20, dx = r - dy * 20;
        int gy = y + dy - 2, gx = x0 + dx - 2;
        float v = 0.f;
        if (gy >= 0 && gy < 128 && gx >= 0 && gx < 128)
            v = x[((size_t)(b * 3 + c) * 128 + gy) * 128 + gx];
        xp[c][dy][dx] = v;
    }
    __syncthreads();

    const int px = x0 + pl;
    const __bf16* ub = Ut + (size_t)b * 400 * 16384 + y * 128 + px;
    float u[25], m = 0.f;
#pragma unroll
    for (int tap = 0; tap < 25; tap++) {
        u[tap] = (float)ub[(size_t)(tap * 16 + s) * 16384];
        m += u[tap];
    }
    m *= 0.04f;
#pragma unroll
    for (int c = 0; c < 3; c++) {
        float a = 0.f;
#pragma unroll
        for (int tap = 0; tap < 25; tap++)
            a = fmaf(xp[c][tap / 5][pl + tap % 5], u[tap] - m + 0.04f, a);
        vs[c][s][pl] = a;
    }
    __syncthreads();

    const size_t Eb = (size_t)b * 3 * 262144;
    for (int i = tid; i < 768; i += 256) {
        int c = i >> 8, r = i & 255;
        int s1 = r >> 6, cc = r & 63;
        float v = vs[c][s1 * 4 + (cc & 3)][cc >> 2];
        size_t o = Eb + (size_t)c * 262144 + (size_t)(y * 4 + s1) * 512 + x0 * 4 + cc;
        out[o] = v + E[o];
    }
}

// ===========================================================================
extern "C" void kernel_launch(void* const* d_in, const int* in_sizes, int n_in,
                              void* d_out, int out_size, void* d_ws, size_t ws_size,
                              hipStream_t stream)
{
    const float* x      = (const float*)d_in[0];
    const float* w_in   = (const float*)d_in[1];
    const float* b_in   = (const float*)d_in[2];
    const float* res_w1 = (const float*)d_in[3];
    const float* res_b1 = (const float*)d_in[4];
    const float* res_w2 = (const float*)d_in[5];
    const float* res_b2 = (const float*)d_in[6];
    const float* r_w1   = (const float*)d_in[7];
    const float* r_b1   = (const float*)d_in[8];
    const float* r_w2   = (const float*)d_in[9];
    const float* r_b2   = (const float*)d_in[10];
    const float* r_w3   = (const float*)d_in[11];
    const float* r_b3   = (const float*)d_in[12];
    const float* k_w1   = (const float*)d_in[13];
    const float* k_b1   = (const float*)d_in[14];
    const float* k_w2   = (const float*)d_in[15];
    const float* k_b2   = (const float*)d_in[16];
    float* out = (float*)d_out;

    char* ws = (char*)d_ws;
    __bf16* WT = (__bf16*)ws;                   // weights, 3.0 MB
    __bf16* F  = (__bf16*)(ws + 3145728);       // [4,128,128,64]   8.4 MB
    __bf16* Hb = (__bf16*)(ws + 11534336);      // [4,128,128,64]   8.4 MB
    __bf16* R1 = (__bf16*)(ws + 19922944);      // [4,128,128,128] 16.8 MB
    __bf16* R2 = (__bf16*)(ws + 36700160);      // [4][4][16][256][256] 33.6 MB
    __bf16* K1 = (__bf16*)(ws + 70254592);      // [4,128,128,128] 16.8 MB
    float*  E  = (float*) (ws + 87031808);      // [4,3,512,512]   12.6 MB
    __bf16* Ut = (__bf16*)(ws + 3145728);       // [4][400][16384] 52.4 MB
                                                // (overlays F..R2, dead by then)

    const int oRes1 = 0, oRes2 = 442368, oRw1 = 884736, oKw1 = 958464,
              oRw2 = 1032192, oKw2 = 1050624;

    WTab tab;
    for (int i = 0; i < 12; i++)
        tab.s[i]      = { res_w1 + (size_t)i * 36864, oRes1 + i * 36864, 64, 64 };
    for (int i = 0; i < 12; i++)
        tab.s[12 + i] = { res_w2 + (size_t)i * 36864, oRes2 + i * 36864, 64, 64 };
    tab.s[24] = { r_w1, oRw1, 128, 64 };
    tab.s[25] = { k_w1, oKw1, 128, 64 };
    tab.s[26] = { r_w2, oRw2, 64, 32 };
    tab.s[27] = { k_w2, oKw2, 400, 128 };

    dim3 blk(256);
    wcvt_k<<<dim3(288, 27), blk, 0, stream>>>(tab, WT, 0);     // segs 0..26
    wcvt_k<<<dim3(1800, 1), blk, 0, stream>>>(tab, WT, 27);    // k_w2

    conv_in_k<<<dim3(64, 4), blk, 0, stream>>>(x, w_in, b_in, F);

    // 12 residual blocks (MT=2, ICB=32 -> 39 KB LDS -> 4 blocks/CU)
    for (int i = 0; i < 12; i++) {
        convm_k<64, 32, 2, 0, 0, true, true, false, false>
            <<<dim3(64, 4, 2), blk, 0, stream>>>(
            F, WT + oRes1 + i * 36864, res_b1 + i * 64, Hb, 128, 128, 64, 0);
        convm_k<64, 32, 2, 0, 0, false, false, true, false>
            <<<dim3(64, 4, 2), blk, 0, stream>>>(
            Hb, WT + oRes2 + i * 36864, res_b2 + i * 64, F, 128, 128, 64, 0);
    }

    // residual branch: r1 (NHWC 128ch) -> r2 (PS2 sub-plane) -> E
    convm_k<64, 32, 2, 0, 0, true, true, false, false>
        <<<dim3(64, 4, 4), blk, 0, stream>>>(
        F, WT + oRw1, r_b1, R1, 128, 128, 128, 0);
    convm_k<32, 32, 2, 1, 2, false, true, false, false>
        <<<dim3(256, 4, 2), blk, 0, stream>>>(
        R1, WT + oRw2, r_b2, R2, 256, 256, 64, 0);
    rw3_k<<<dim3(256, 4), blk, 0, stream>>>(R2, r_w3, r_b3, E);

    // kernel branch stem: k1 = relu(conv(relu(f)))
    convm_k<64, 32, 2, 0, 0, true, true, false, false>
        <<<dim3(64, 4, 4), blk, 0, stream>>>(
        F, WT + oKw1, k_b1, K1, 128, 128, 128, 0);

    // up-kernel GEMM, all batches, 400 ocs via 13 z-blocks of 32 (tail guarded)
    convm_k<128, 32, 2, 0, 1, false, false, false, true>
        <<<dim3(64, 4, 13), blk, 0, stream>>>(
        K1, WT + oKw2, k_b2, Ut, 128, 128, 400, 0);

    // normalize + dynamic filter + PS4 + residual
    filter_k<<<dim3(1024, 4), blk, 0, stream>>>(Ut, x, E, out);
}

// Round 6
// 576.882 us; speedup vs baseline: 38.1143x; 1.1603x over previous
//
#include <hip/hip_runtime.h>
#include <stdint.h>

typedef __attribute__((ext_vector_type(8))) __bf16 bf16x8;
typedef __attribute__((ext_vector_type(4))) float f32x4;

__device__ inline f32x4 MFMA(bf16x8 a, bf16x8 b, f32x4 c) {
    return __builtin_amdgcn_mfma_f32_16x16x32_bf16(a, b, c, 0, 0, 0);
}

// ===========================================================================
// Weight convert+transpose: fp32 [OC][IC][3][3] -> bf16 [9][OC][IC]
// ===========================================================================
struct WSeg { const float* src; int off, OC, IC; };
struct WTab { WSeg s[28]; };

__global__ __launch_bounds__(256) void wcvt_k(WTab tab, __bf16* dst, int seg0) {
    const WSeg sg = tab.s[seg0 + blockIdx.y];
    int n = sg.OC * sg.IC * 9;
    int e = blockIdx.x * 256 + threadIdx.x;
    if (e >= n) return;
    int ic9 = sg.IC * 9;
    int oc = e / ic9;
    int r  = e - oc * ic9;
    int ic = r / 9;
    int t  = r - ic * 9;
    dst[(size_t)sg.off + ((size_t)t * sg.OC + oc) * sg.IC + ic] = (__bf16)sg.src[e];
}

// ===========================================================================
// conv_in: 3->64 fp32 planar in, bf16 NHWC out. 16x16 tile, 1 px/thread.
// ===========================================================================
__global__ __launch_bounds__(256) void conv_in_k(
    const float* __restrict__ x, const float* __restrict__ w,
    const float* __restrict__ bias, __bf16* __restrict__ out)
{
    const int tid = threadIdx.x;
    const int ty = (blockIdx.x >> 3) * 16, tx = (blockIdx.x & 7) * 16;
    const int b = blockIdx.y;
    __shared__ float xs[3][18][18];
    __shared__ float wl[27][64];
    for (int i = tid; i < 27 * 64; i += 256) {
        int t = i >> 6, oc = i & 63;
        wl[t][oc] = w[oc * 27 + t];
    }
    for (int i = tid; i < 3 * 324; i += 256) {
        int c = i / 324, r = i - c * 324;
        int y = r / 18, xx = r - y * 18;
        int gy = ty + y - 1, gx = tx + xx - 1;
        float v = 0.f;
        if (gy >= 0 && gy < 128 && gx >= 0 && gx < 128)
            v = x[((size_t)(b * 3 + c) * 128 + gy) * 128 + gx];
        xs[c][y][xx] = v;
    }
    __syncthreads();
    const int py = tid >> 4, px = tid & 15;
    float acc[64];
#pragma unroll
    for (int o = 0; o < 64; o++) acc[o] = bias[o];
    for (int c = 0; c < 3; c++)
        for (int t = 0; t < 9; t++) {
            float p = xs[c][py + t / 3][px + t % 3];
            const float* wr = &wl[c * 9 + t][0];
#pragma unroll
            for (int o = 0; o < 64; o++) acc[o] = fmaf(p, wr[o], acc[o]);
        }
    __bf16* op = out + (((size_t)b * 16384) + (ty + py) * 128 + (tx + px)) * 64;
    for (int o = 0; o < 64; o += 8) {
        union { bf16x8 v; uint4 u; } pk;
#pragma unroll
        for (int j = 0; j < 8; j++) pk.v[j] = (__bf16)acc[o + j];
        *(uint4*)(op + o) = pk.u;
    }
}

// ===========================================================================
// MFMA 3x3 conv. NHWC bf16 in, wt [9][OCALL][CIN] bf16.
// 16x16 px tile, 4 waves; wave = M=MT*16 oc x N=64 px (4 rows of 16).
// STAGE: 0 = direct NHWC; 1 = PS2 gather from NHWC[4*CIN] at half res
//        (vectorized: reads uint4 rows, extracts 2 matching sub-channels).
// OUTM: 0 = NHWC bf16 (stride OCALL, optional OCGUARD tail mask);
//       2 = PS2 sub-plane NHWC16: [b][sub][H][W][OCALL/4].
// ===========================================================================
template<int CIN, int ICB, int MT, int STAGE, int OUTM,
         bool RELU_IN, bool RELU_OUT, bool ACCUM, bool OCGUARD>
__global__ __launch_bounds__(256) void convm_k(
    const __bf16* __restrict__ in, const __bf16* __restrict__ wt,
    const float* __restrict__ bias, void* __restrict__ outv,
    int H, int W, int OCALL, int ocb0)
{
    constexpr int M = MT * 16;
    constexpr int CHUNKS = CIN / ICB;
    constexpr int GR = ICB / 8;               // 16B groups per row
    constexpr int GM = (GR >= 8 ? 7 : GR - 1);
    constexpr int KS = ICB / 32;

    const int tid = threadIdx.x;
    const int ntx = W >> 4;
    const int h0 = (blockIdx.x / ntx) << 4;
    const int w0 = (blockIdx.x % ntx) << 4;
    const int b = blockIdx.y;
    const int ocb = ocb0 + blockIdx.z * M;

    __shared__ __bf16 inT[324 * ICB];
    __shared__ __bf16 wT[9 * M * ICB];

    const int lane = tid & 63;
    const int wv = tid >> 6;
    const int cl = lane & 15;     // col (pixel-x / oc-low for A rows)
    const int kg = lane >> 4;     // k-group
    const int row0 = wv << 2;

    f32x4 acc[MT][4];
#pragma unroll
    for (int m = 0; m < MT; m++) {
        f32x4 bv;
#pragma unroll
        for (int j = 0; j < 4; j++) {
            int o = ocb + m * 16 + kg * 4 + j;
            bv[j] = (!OCGUARD || o < OCALL) ? bias[o] : 0.f;
        }
#pragma unroll
        for (int n = 0; n < 4; n++) acc[m][n] = bv;
    }

    for (int c = 0; c < CHUNKS; c++) {
        if (c) __syncthreads();
        // ---- stage input halo tile (18x18) for this ic chunk
        if (STAGE == 0) {
            for (int i = tid; i < 324 * GR; i += 256) {
                int pix = i / GR, g = i - pix * GR;
                int y = pix / 18, xx = pix - y * 18;
                int gy = h0 + y - 1, gx = w0 + xx - 1;
                union { uint4 u; bf16x8 v; unsigned short us[8]; } d;
                d.u = make_uint4(0u, 0u, 0u, 0u);
                if (gy >= 0 && gy < H && gx >= 0 && gx < W) {
                    d.u = *(const uint4*)(in + (((size_t)(b * H + gy)) * W + gx) * CIN
                                          + c * ICB + g * 8);
                    if (RELU_IN) {
#pragma unroll
                        for (int j = 0; j < 8; j++)
                            if (d.us[j] & 0x8000u) d.us[j] = 0;
                    }
                }
                int sg = (g & ~GM) | ((g ^ pix) & GM);
                *(bf16x8*)(inT + pix * ICB + sg * 8) = d.v;
            }
        } else {
            // PS2 gather from NHWC[4*CIN] at half res, vectorized uint4 reads
            const int SRCH = H >> 1, SRCW = W >> 1, SRCC = 4 * CIN;
            constexpr int NG = ICB / 2;       // uint4 tasks per pixel
            for (int i = tid; i < 324 * NG; i += 256) {
                int pix = i / NG, g = i - pix * NG;   // g indexes src 8-ch group
                int y = pix / 18, xx = pix - y * 18;
                int gy = h0 + y - 1, gx = w0 + xx - 1;
                union { uint4 u; __bf16 hx[8]; } d;
                d.u = make_uint4(0u, 0u, 0u, 0u);
                int sub = 0;
                if (gy >= 0 && gy < H && gx >= 0 && gx < W) {
                    sub = ((gy & 1) << 1) | (gx & 1);
                    d.u = *(const uint4*)(in
                        + (((size_t)(b * SRCH + (gy >> 1))) * SRCW + (gx >> 1)) * SRCC
                        + c * ICB * 4 + g * 8);
                }
                __bf16 v0 = d.hx[sub], v1 = d.hx[4 + sub];
                int e0 = 2 * g;                    // dest channels e0, e0+1
                int gr = e0 >> 3;
                int sg = (gr & ~GM) | ((gr ^ pix) & GM);
                inT[pix * ICB + sg * 8 + (e0 & 7)] = v0;
                inT[pix * ICB + sg * 8 + ((e0 & 7) + 1)] = v1;
            }
        }
        // ---- stage weights for this chunk: [t][oc][ic] swizzled by oc
        for (int i = tid; i < 9 * M * GR; i += 256) {
            int t = i / (M * GR), r = i - t * (M * GR);
            int oc = r / GR, g = r - oc * GR;
            int ocr = ocb + oc;
            if (OCGUARD) ocr = (ocr < OCALL) ? ocr : (OCALL - 1);
            union { uint4 u; bf16x8 v; } d;
            d.u = *(const uint4*)(wt + ((size_t)t * OCALL + ocr) * CIN
                                  + c * ICB + g * 8);
            int sg = (g & ~GM) | ((g ^ oc) & GM);
            *(bf16x8*)(wT + ((t * M) + oc) * ICB + sg * 8) = d.v;
        }
        __syncthreads();

        // ---- 9 taps x K-steps of MFMA
#pragma unroll
        for (int t = 0; t < 9; t++) {
            const int dy = t / 3, dx = t % 3;
            const __bf16* wb = wT + t * M * ICB;
#pragma unroll
            for (int ks = 0; ks < KS; ks++) {
                bf16x8 af[MT], bfr[4];
#pragma unroll
                for (int m = 0; m < MT; m++) {
                    int oc = m * 16 + cl;
                    int g = ks * 4 + kg;
                    int sg = (g & ~GM) | ((g ^ oc) & GM);
                    af[m] = *(const bf16x8*)(wb + oc * ICB + sg * 8);
                }
#pragma unroll
                for (int n = 0; n < 4; n++) {
                    int pix = (row0 + n + dy) * 18 + cl + dx;
                    int g = ks * 4 + kg;
                    int sg = (g & ~GM) | ((g ^ pix) & GM);
                    bfr[n] = *(const bf16x8*)(inT + pix * ICB + sg * 8);
                }
#pragma unroll
                for (int m = 0; m < MT; m++)
#pragma unroll
                    for (int n = 0; n < 4; n++)
                        acc[m][n] = MFMA(af[m], bfr[n], acc[m][n]);
            }
        }
    }

    // ---- epilogue. C frag: col(pixel-x)=cl, oc = m*16 + kg*4 + j
    if (OUTM == 0) {
        __bf16* outp = (__bf16*)outv;
#pragma unroll
        for (int m = 0; m < MT; m++) {
            int oc = ocb + m * 16 + kg * 4;
            if (!OCGUARD || oc < OCALL) {
#pragma unroll
                for (int n = 0; n < 4; n++) {
                    __bf16* op = outp + (((size_t)(b * H + h0 + row0 + n)) * W + (w0 + cl))
                                     * OCALL + oc;
                    f32x4 v = acc[m][n];
                    if (ACCUM) {
                        union { uint2 u; __bf16 hx[4]; } old;
                        old.u = *(const uint2*)op;
#pragma unroll
                        for (int j = 0; j < 4; j++) v[j] += (float)old.hx[j];
                    }
                    union { uint2 u; __bf16 hx[4]; } pk;
#pragma unroll
                    for (int j = 0; j < 4; j++) {
                        float f = v[j];
                        if (RELU_OUT) f = fmaxf(f, 0.f);
                        pk.hx[j] = (__bf16)f;
                    }
                    *(uint2*)op = pk.u;
                }
            }
        }
    } else {   // OUTM == 2: PS2 sub-plane NHWC16 [b][sub][H][W][OCALL/4]
        __bf16* outp = (__bf16*)outv;
        const int HW = H * W;
        const int CP = OCALL >> 2;
#pragma unroll
        for (int m = 0; m < MT; m++) {
            int cc = (ocb + m * 16 + kg * 4) >> 2;   // channel in sub-plane
#pragma unroll
            for (int n = 0; n < 4; n++) {
                int pix = (h0 + row0 + n) * W + w0 + cl;
#pragma unroll
                for (int j = 0; j < 4; j++) {        // j == subpixel index
                    float f = acc[m][n][j];
                    if (RELU_OUT) f = fmaxf(f, 0.f);
                    outp[((size_t)(b * 4 + j) * HW + pix) * CP + cc] = (__bf16)f;
                }
            }
        }
    }
}

// ===========================================================================
// r_w3: 16->3 conv @512^2 from PS2 sub-plane NHWC16 r2 [b][4][256][256][16].
// Block: 16x16 LR tile -> 32x32 HR out. Thread: 4 consecutive HR px.
// ===========================================================================
__global__ __launch_bounds__(256) void rw3_k(
    const __bf16* __restrict__ r2p, const float* __restrict__ w,
    const float* __restrict__ bias, float* __restrict__ E)
{
    const int tid = threadIdx.x;
    const int tY = (blockIdx.x >> 4) * 16;
    const int tX = (blockIdx.x & 15) * 16;
    const int b = blockIdx.y;

    __shared__ __bf16 xs[4][18][18][16];   // [sub][y][x][ch]
    __shared__ float wl[3][9][16];
    for (int i = tid; i < 432; i += 256) {
        int oc = i / 144, r = i - oc * 144;
        int t = r >> 4, e = r & 15;
        wl[oc][t][e] = w[(oc * 16 + e) * 9 + t];
    }
    // stage: task = (sub, y, g) ; g = 16B group (half a pixel's 16 channels)
    for (int i = tid; i < 4 * 18 * 36; i += 256) {
        int g = i % 36; int r = i / 36;
        int y = r % 18, sub = r / 18;
        int px = g >> 1, half = g & 1;
        int gy = tY + y - 1, gx = tX + px - 1;
        uint4 v = make_uint4(0u, 0u, 0u, 0u);
        if (gy >= 0 && gy < 256 && gx >= 0 && gx < 256)
            v = *(const uint4*)(r2p
                + (((size_t)(b * 4 + sub) << 16) + (gy << 8) + gx) * 16 + half * 8);
        *(uint4*)(&xs[sub][y][px][half * 8]) = v;
    }
    __syncthreads();

    const int hyl = tid >> 3;           // 0..31
    const int hx0 = (tid & 7) * 4;      // 0..28
    float acc[3][4];
#pragma unroll
    for (int oc = 0; oc < 3; oc++)
#pragma unroll
        for (int p = 0; p < 4; p++) acc[oc][p] = bias[oc];

#pragma unroll
    for (int dy = 0; dy < 3; dy++) {
        int hy = hyl + dy - 1;
        int ys = (hy >> 1) + 1;
        int suby = (hy & 1) << 1;
#pragma unroll
        for (int dx = 0; dx < 3; dx++) {
            const int t = dy * 3 + dx;
#pragma unroll
            for (int p = 0; p < 4; p++) {
                int hx = hx0 + p + dx - 1;
                int sub = suby | (hx & 1);
                int xsx = (hx >> 1) + 1;
                const __bf16* bp = &xs[sub][ys][xsx][0];
                bf16x8 v0 = *(const bf16x8*)bp;
                bf16x8 v1 = *(const bf16x8*)(bp + 8);
#pragma unroll
                for (int e = 0; e < 8; e++) {
                    float f0 = (float)v0[e], f1 = (float)v1[e];
                    acc[0][p] = fmaf(f0, wl[0][t][e], acc[0][p]);
                    acc[1][p] = fmaf(f0, wl[1][t][e], acc[1][p]);
                    acc[2][p] = fmaf(f0, wl[2][t][e], acc[2][p]);
                    acc[0][p] = fmaf(f1, wl[0][t][e + 8], acc[0][p]);
                    acc[1][p] = fmaf(f1, wl[1][t][e + 8], acc[1][p]);
                    acc[2][p] = fmaf(f1, wl[2][t][e + 8], acc[2][p]);
                }
            }
        }
    }
    const int HY = tY * 2 + hyl, HX = tX * 2 + hx0;
#pragma unroll
    for (int oc = 0; oc < 3; oc++) {
        float4 v = make_float4(acc[oc][0], acc[oc][1], acc[oc][2], acc[oc][3]);
        *(float4*)&E[(((size_t)(b * 3 + oc)) << 18) + HY * 512 + HX] = v;
    }
}

// ===========================================================================
// filter: normalize + dynamic 5x5 + PS4 + residual. Ut NHWC [b][16384][400].
// LDS-staged Ut tile (16 px x 400 ch, coalesced 800B rows).
// ===========================================================================
__global__ __launch_bounds__(256) void filter_k(
    const __bf16* __restrict__ Ut, const float* __restrict__ x,
    const float* __restrict__ E, float* __restrict__ out)
{
    const int tid = threadIdx.x;
    const int s  = tid >> 4;    // subpixel 0..15
    const int pl = tid & 15;    // pixel lane
    const int b  = blockIdx.y;
    const int pix0 = blockIdx.x * 16;
    const int y  = pix0 >> 7;
    const int x0 = pix0 & 127;

    __shared__ float xp[3][5][20];
    __shared__ float vs[3][16][16];    // [c][s][pl]
    __shared__ __bf16 ut[16][408];     // [px][ch], padded row

    for (int i = tid; i < 800; i += 256) {         // 16 px x 50 groups of 8
        int px = i / 50, g = i - px * 50;
        uint4 v = *(const uint4*)(Ut + ((size_t)(b * 16384 + pix0 + px) * 400 + g * 8));
        *(uint4*)(&ut[px][g * 8]) = v;
    }
    for (int i = tid; i < 300; i += 256) {
        int c = i / 100, r = i - c * 100;
        int dy = r / 20, dx = r - dy * 20;
        int gy = y + dy - 2, gx = x0 + dx - 2;
        float v = 0.f;
        if (gy >= 0 && gy < 128 && gx >= 0 && gx < 128)
            v = x[((size_t)(b * 3 + c) * 128 + gy) * 128 + gx];
        xp[c][dy][dx] = v;
    }
    __syncthreads();

    float u[25], m = 0.f;
#pragma unroll
    for (int tap = 0; tap < 25; tap++) {
        u[tap] = (float)ut[pl][tap * 16 + s];
        m += u[tap];
    }
    m *= 0.04f;
#pragma unroll
    for (int c = 0; c < 3; c++) {
        float a = 0.f;
#pragma unroll
        for (int tap = 0; tap < 25; tap++)
            a = fmaf(xp[c][tap / 5][pl + tap % 5], u[tap] - m + 0.04f, a);
        vs[c][s][pl] = a;
    }
    __syncthreads();

    const size_t Eb = (size_t)b * 3 * 262144;
    for (int i = tid; i < 768; i += 256) {
        int c = i >> 8, r = i & 255;
        int s1 = r >> 6, cc = r & 63;
        float v = vs[c][s1 * 4 + (cc & 3)][cc >> 2];
        size_t o = Eb + (size_t)c * 262144 + (size_t)(y * 4 + s1) * 512 + x0 * 4 + cc;
        out[o] = v + E[o];
    }
}

// ===========================================================================
extern "C" void kernel_launch(void* const* d_in, const int* in_sizes, int n_in,
                              void* d_out, int out_size, void* d_ws, size_t ws_size,
                              hipStream_t stream)
{
    const float* x      = (const float*)d_in[0];
    const float* w_in   = (const float*)d_in[1];
    const float* b_in   = (const float*)d_in[2];
    const float* res_w1 = (const float*)d_in[3];
    const float* res_b1 = (const float*)d_in[4];
    const float* res_w2 = (const float*)d_in[5];
    const float* res_b2 = (const float*)d_in[6];
    const float* r_w1   = (const float*)d_in[7];
    const float* r_b1   = (const float*)d_in[8];
    const float* r_w2   = (const float*)d_in[9];
    const float* r_b2   = (const float*)d_in[10];
    const float* r_w3   = (const float*)d_in[11];
    const float* r_b3   = (const float*)d_in[12];
    const float* k_w1   = (const float*)d_in[13];
    const float* k_b1   = (const float*)d_in[14];
    const float* k_w2   = (const float*)d_in[15];
    const float* k_b2   = (const float*)d_in[16];
    float* out = (float*)d_out;

    char* ws = (char*)d_ws;
    __bf16* WT = (__bf16*)ws;                   // weights, 3.0 MB
    __bf16* F  = (__bf16*)(ws + 3145728);       // [4,128,128,64]   8.4 MB
    __bf16* Hb = (__bf16*)(ws + 11534336);      // [4,128,128,64]   8.4 MB
    __bf16* R1 = (__bf16*)(ws + 19922944);      // [4,128,128,128] 16.8 MB
    __bf16* R2 = (__bf16*)(ws + 36700160);      // [4][4][256][256][16] 33.6 MB
    __bf16* K1 = (__bf16*)(ws + 70254592);      // [4,128,128,128] 16.8 MB
    float*  E  = (float*) (ws + 87031808);      // [4,3,512,512]   12.6 MB
    __bf16* Ut = (__bf16*)(ws + 3145728);       // [4][16384][400] 52.4 MB
                                                // (overlays F..R2-head, dead by then)

    const int oRes1 = 0, oRes2 = 442368, oRw1 = 884736, oKw1 = 958464,
              oRw2 = 1032192, oKw2 = 1050624;

    WTab tab;
    for (int i = 0; i < 12; i++)
        tab.s[i]      = { res_w1 + (size_t)i * 36864, oRes1 + i * 36864, 64, 64 };
    for (int i = 0; i < 12; i++)
        tab.s[12 + i] = { res_w2 + (size_t)i * 36864, oRes2 + i * 36864, 64, 64 };
    tab.s[24] = { r_w1, oRw1, 128, 64 };
    tab.s[25] = { k_w1, oKw1, 128, 64 };
    tab.s[26] = { r_w2, oRw2, 64, 32 };
    tab.s[27] = { k_w2, oKw2, 400, 128 };

    dim3 blk(256);
    wcvt_k<<<dim3(288, 27), blk, 0, stream>>>(tab, WT, 0);     // segs 0..26
    wcvt_k<<<dim3(1800, 1), blk, 0, stream>>>(tab, WT, 27);    // k_w2

    conv_in_k<<<dim3(64, 4), blk, 0, stream>>>(x, w_in, b_in, F);

    // 12 residual blocks (MT=2, ICB=32 -> 39 KB LDS -> 4 blocks/CU)
    for (int i = 0; i < 12; i++) {
        convm_k<64, 32, 2, 0, 0, true, true, false, false>
            <<<dim3(64, 4, 2), blk, 0, stream>>>(
            F, WT + oRes1 + i * 36864, res_b1 + i * 64, Hb, 128, 128, 64, 0);
        convm_k<64, 32, 2, 0, 0, false, false, true, false>
            <<<dim3(64, 4, 2), blk, 0, stream>>>(
            Hb, WT + oRes2 + i * 36864, res_b2 + i * 64, F, 128, 128, 64, 0);
    }

    // residual branch: r1 (NHWC128) -> r2 (PS2 sub-plane NHWC16) -> E
    convm_k<64, 32, 2, 0, 0, true, true, false, false>
        <<<dim3(64, 4, 4), blk, 0, stream>>>(
        F, WT + oRw1, r_b1, R1, 128, 128, 128, 0);
    convm_k<32, 32, 2, 1, 2, false, true, false, false>
        <<<dim3(256, 4, 2), blk, 0, stream>>>(
        R1, WT + oRw2, r_b2, R2, 256, 256, 64, 0);
    rw3_k<<<dim3(256, 4), blk, 0, stream>>>(R2, r_w3, r_b3, E);

    // kernel branch stem: k1 = relu(conv(relu(f)))
    convm_k<64, 32, 2, 0, 0, true, true, false, false>
        <<<dim3(64, 4, 4), blk, 0, stream>>>(
        F, WT + oKw1, k_b1, K1, 128, 128, 128, 0);

    // up-kernel GEMM -> Ut NHWC [b][16384][400] (13 z-blocks of 32, tail guarded)
    convm_k<128, 32, 2, 0, 0, false, false, false, true>
        <<<dim3(64, 4, 13), blk, 0, stream>>>(
        K1, WT + oKw2, k_b2, Ut, 128, 128, 400, 0);

    // normalize + dynamic filter + PS4 + residual
    filter_k<<<dim3(1024, 4), blk, 0, stream>>>(Ut, x, E, out);
}